// Round 2
// baseline (931.622 us; speedup 1.0000x reference)
//
#include <hip/hip_runtime.h>
#include <stdint.h>

// GNN_Layer on MI355X.
// h = relu( xf@W^T + (a_ud@xf)@W_ud^T + (a_lr@xf)@W_lr^T + biases + hg@W_go^T + b_go )
// Restructured: C[8192,512] = a_ud@Y_ud + a_lr@Y_lr + xf@W^T  (K = 16896 concatenated),
// row_add[j] folds all biases + global branch; epilogue relu.
//
// R5 = R4 resubmit (R4 bench died on container infra, no signal).
// R3 -> R4 (latency fix for k5 — counted-vmcnt pipeline):
//  k5 was latency-bound (MfmaUtil 13.7, VALU 8.7, HBM 25% — nothing saturated; 3x off
//  its 136us memory roofline). Cause: A (a_ud/a_lr, 536 MB fp32, read-once => cold HBM
//  ~900cy) was only 1 step ahead, and __syncthreads' vmcnt(0) drain forced every step
//  to eat the full latency.
//  * A-loads now 2 steps ahead in registers (two rotating float4x4 sets, +32 VGPR),
//    pack->LDS stays 1 step ahead. launch_bounds (256,3) so no spills (~150 VGPR).
//  * raw s_barrier + manual counted s_waitcnt: per step, issue B(s+1) gloads FIRST,
//    then A(s+2) reg loads (sched_barrier(0)-pinned order); end-of-step
//    "vmcnt(4) lgkmcnt(0)" retires exactly B(s+1) and keeps A(s+2) in flight across
//    the barrier (never drain to 0 in the main loop; tail uses vmcnt(0)).
//  * k2 upgraded: m97-style double-buffered staging (was fully serial load->sync->
//    compute) + same chunk-XOR swizzle as k5 on its 64B LDS rows.
//  LDS layout, tiles (128x128, BK=32), split-K x4, swizzles unchanged from R3.
//
// Workspace:
//   xb      bf16[8192][512]   @ 0
//   Yt      bf16[512][16896]  @ 8,388,608    k<8192: Y_ud^T | <16384: Y_lr^T | tail: W
//   Wb1     bf16[1536][512]   @ 25,690,112   rows: W_ud | W_lr | W_g
//   colsum  f32[512]          @ 27,262,976
//   row_add f32[512]          @ 27,265,024
//   P       f32[Z-1][8192][512] @ 27,267,072 split-K partials

typedef __attribute__((ext_vector_type(8))) short short8;   // 8 bf16 = 4 VGPRs
typedef __attribute__((ext_vector_type(4))) float f32x4;    // MFMA C/D frag

typedef const __attribute__((address_space(1))) void* gas1_t;
typedef __attribute__((address_space(3))) void* las3_t;

__device__ __forceinline__ void gload16(const void* g, void* l) {
  __builtin_amdgcn_global_load_lds((gas1_t)g, (las3_t)l, 16, 0, 0);
}

// pack two fp32 -> two bf16 by truncation (top halves), one v_perm_b32
__device__ __forceinline__ unsigned pack2t(float lo, float hi) {
  return __builtin_amdgcn_perm(__float_as_uint(hi), __float_as_uint(lo), 0x07060302u);
}

// round-to-nearest-even fp32 -> bf16
__device__ __forceinline__ unsigned f2bf_rne(float f) {
  unsigned u = __float_as_uint(f);
  return (u + 0x7FFFu + ((u >> 16) & 1u)) >> 16;
}
__device__ __forceinline__ unsigned pack2_rne(float lo, float hi) {
  return f2bf_rne(lo) | (f2bf_rne(hi) << 16);
}

// ---------------- K1: dtype conversion ----------------
__global__ __launch_bounds__(256) void k1_convert(
    const float* __restrict__ x, const float* __restrict__ W,
    const float* __restrict__ W_ud, const float* __restrict__ W_lr,
    const float* __restrict__ W_g,
    uint16_t* __restrict__ xb, uint16_t* __restrict__ Yt, uint16_t* __restrict__ Wb1)
{
  unsigned tid = blockIdx.x * 256u + threadIdx.x;   // 0..655359
  const float* src;
  uint16_t* dst;
  if (tid < 524288u) {
    src = x + (size_t)tid * 8;
    dst = xb + (size_t)tid * 8;
  } else {
    unsigned r = tid - 524288u;
    unsigned which = r >> 15;              // 0:W 1:W_ud 2:W_lr 3:W_g
    unsigned e8 = (r & 32767u) * 8;
    src = (which == 0 ? W : which == 1 ? W_ud : which == 2 ? W_lr : W_g) + e8;
    if (which == 0) {
      unsigned n = e8 >> 9, k = e8 & 511u;
      dst = Yt + (size_t)n * 16896 + 16384 + k;
    } else {
      dst = Wb1 + (size_t)(which - 1) * 262144 + e8;
    }
  }
  float4 v0 = ((const float4*)src)[0];
  float4 v1 = ((const float4*)src)[1];
  uint4 p;
  p.x = pack2_rne(v0.x, v0.y); p.y = pack2_rne(v0.z, v0.w);
  p.z = pack2_rne(v1.x, v1.y); p.w = pack2_rne(v1.z, v1.w);
  *(uint4*)dst = p;
}

// ---------------- K2: small GEMM  Z = xb @ Wb1^T  (M=8192, N=1536, K=512) ----------------
// blockIdx.y 0-3 -> Y_ud^T; 4-7 -> Y_lr^T; 8-11 -> colsum += mask*relu(Z+b_g)
// R4: double-buffered staging (issue s+1 before computing s; __syncthreads at the
// top of each step drains the previous step's loads only) + chunk-XOR swizzle so
// the 64B LDS rows are bank-conflict-free on ds_read_b128.
__global__ __launch_bounds__(256) void k2_gemm1(
    const uint16_t* __restrict__ xb, const uint16_t* __restrict__ Wb1,
    const float* __restrict__ mask, const float* __restrict__ b_g,
    uint16_t* __restrict__ Yt, float* __restrict__ colsum)
{
  __shared__ __align__(16) char smem[34816];
  char* const A0 = smem;
  char* const B0 = smem + 8192;
  char* const A1 = smem + 16384;
  char* const B1 = smem + 24576;

  const int t = threadIdx.x;
  const int i0 = blockIdx.x * 128;
  const int bn = blockIdx.y;
  const int n0 = bn * 128;
  const int lane = t & 63, w = t >> 6;
  const int q = lane >> 4, l15 = lane & 15;
  const int wm = w >> 1, wn = w & 1;
  const int srow = t >> 2;
  const int sw = (t & 3) ^ ((srow >> 1) & 3);   // swizzled source chunk

  f32x4 acc[4][4] = {};

  const uint16_t* const aA0 = xb + (size_t)(i0 + srow) * 512 + sw * 8;
  const uint16_t* const aA1 = aA0 + (size_t)64 * 512;
  const uint16_t* const aB0 = Wb1 + (size_t)(n0 + srow) * 512 + sw * 8;
  const uint16_t* const aB1 = aB0 + (size_t)64 * 512;

  // prologue: stage step 0
  gload16(aA0, A0 + t * 16);
  gload16(aA1, A0 + 4096 + t * 16);
  gload16(aB0, B0 + t * 16);
  gload16(aB1, B0 + 4096 + t * 16);

  for (int s = 0; s < 16; ++s) {
    __syncthreads();                       // drains step-s loads (issued last iter)
    if (s < 15) {
      const int kk = (s + 1) << 5;
      char* const nA = (s & 1) ? A0 : A1;
      char* const nB = (s & 1) ? B0 : B1;
      gload16(aA0 + kk, nA + t * 16);
      gload16(aA1 + kk, nA + 4096 + t * 16);
      gload16(aB0 + kk, nB + t * 16);
      gload16(aB1 + kk, nB + 4096 + t * 16);
    }
    char* const cA = (s & 1) ? A1 : A0;
    char* const cB = (s & 1) ? B1 : B0;
    short8 af[4], bf[4];
#pragma unroll
    for (int mi = 0; mi < 4; ++mi) {
      const int r = wm * 64 + mi * 16 + l15;
      af[mi] = *(const short8*)(cA + r * 64 + ((q ^ ((r >> 1) & 3)) * 16));
    }
#pragma unroll
    for (int ni = 0; ni < 4; ++ni) {
      const int r = wn * 64 + ni * 16 + l15;
      bf[ni] = *(const short8*)(cB + r * 64 + ((q ^ ((r >> 1) & 3)) * 16));
    }
#pragma unroll
    for (int mi = 0; mi < 4; ++mi)
#pragma unroll
      for (int ni = 0; ni < 4; ++ni)
        acc[mi][ni] = __builtin_amdgcn_mfma_f32_16x16x32_bf16(af[mi], bf[ni], acc[mi][ni], 0, 0, 0);
  }
  __syncthreads();

  const int g = bn >> 2;            // 0: ud, 1: lr, 2: g-branch
  const int jb = (bn & 3) * 128;

  if (g < 2) {
    // transpose 128x128 tile through LDS, emit bf16 rows of Yt
    uint16_t* T = (uint16_t*)smem;  // [128][136]
#pragma unroll
    for (int mi = 0; mi < 4; ++mi) {
#pragma unroll
      for (int ni = 0; ni < 4; ++ni) {
        int jl = wn * 64 + ni * 16 + l15;
#pragma unroll
        for (int r = 0; r < 4; ++r) {
          int il = wm * 64 + mi * 16 + q * 4 + r;
          T[jl * 136 + il] = (uint16_t)f2bf_rne(acc[mi][ni][r]);
        }
      }
    }
    __syncthreads();
    const int jl = t >> 1, half = t & 1;
    uint16_t* dst = Yt + (size_t)(jb + jl) * 16896 + (size_t)g * 8192 + i0 + half * 64;
    const uint16_t* srcT = T + jl * 136 + half * 64;
#pragma unroll
    for (int c = 0; c < 8; ++c)
      *(uint4*)(dst + c * 8) = *(const uint4*)(srcT + c * 8);
  } else {
    // fused global-branch reduction: colsum[j] += sum_i mask[i]*relu(Z[i][j]+b_g[j])
    float mk[4][4];
#pragma unroll
    for (int mi = 0; mi < 4; ++mi)
#pragma unroll
      for (int r = 0; r < 4; ++r)
        mk[mi][r] = mask[i0 + wm * 64 + mi * 16 + q * 4 + r];
#pragma unroll
    for (int ni = 0; ni < 4; ++ni) {
      const int jl = jb + wn * 64 + ni * 16 + l15;
      const float bg = b_g[jl];
      float p = 0.f;
#pragma unroll
      for (int mi = 0; mi < 4; ++mi)
#pragma unroll
        for (int r = 0; r < 4; ++r)
          p += fmaxf(acc[mi][ni][r] + bg, 0.f) * mk[mi][r];
      p += __shfl_xor(p, 16);
      p += __shfl_xor(p, 32);
      if (q == 0) atomicAdd(&colsum[jl], p);
    }
  }
}

// ---------------- K4: h_g, row_add ----------------
__global__ __launch_bounds__(256) void k4_finalize(
    const float* __restrict__ colsum, const float* __restrict__ mask,
    const float* __restrict__ b, const float* __restrict__ b_ud,
    const float* __restrict__ b_lr, const float* __restrict__ W_go,
    const float* __restrict__ b_go,
    float* __restrict__ row_add, float* __restrict__ out_hg)
{
  __shared__ float red[256];
  __shared__ float hg[512];
  const int t = threadIdx.x;
  float s = 0.f;
  for (int k = t; k < 8192; k += 256) s += mask[k];
  red[t] = s;
  __syncthreads();
  for (int o = 128; o > 0; o >>= 1) {
    if (t < o) red[t] += red[t + o];
    __syncthreads();
  }
  const float n = red[0];
  for (int j = t; j < 512; j += 256) hg[j] = colsum[j] / n;
  __syncthreads();

  const int j0 = blockIdx.x * 64;
  const int jj = j0 + (t >> 2);
  const int seg = t & 3;
  const float4* wrow = (const float4*)(W_go + (size_t)jj * 512 + seg * 128);
  float p = 0.f;
#pragma unroll 4
  for (int c = 0; c < 32; ++c) {
    float4 wv = wrow[c];
    const float* h4 = &hg[seg * 128 + c * 4];
    p += wv.x * h4[0] + wv.y * h4[1] + wv.z * h4[2] + wv.w * h4[3];
  }
  p += __shfl_down(p, 2);
  p += __shfl_down(p, 1);
  if ((t & 3) == 0)
    row_add[jj] = b[jj] + b_ud[jj] + b_lr[jj] + b_go[jj] + p;
  if (t < 64) out_hg[j0 + t] = hg[j0 + t];
}

// ---------------- K5: big GEMM, K=16896, split-K xZ ----------------
// BM=128 BN=128 BK=32; grid (64, 4, Z); nsteps = (16896/Z)/32 per block.
// A fp32 -> regs (2 steps ahead) -> bf16 pack -> LDS (72B-padded rows, 1 step ahead).
// B (Yt bf16) via global_load_lds 1 step ahead, chunk ^ ((row>>1)&3) source-side
// swizzle. Raw s_barrier + counted s_waitcnt: B(s+1) issued BEFORE A(s+2) so the
// end-of-step vmcnt(4) retires exactly B(s+1) and leaves A(s+2) in flight.
// z=0 -> out, z>0 -> P[(z-1)]; K6 combines.
__global__ __launch_bounds__(256, 3) void k5_gemm_big(
    const float* __restrict__ a_ud, const float* __restrict__ a_lr,
    const float* __restrict__ x, const uint16_t* __restrict__ Yt,
    float* __restrict__ out, float* __restrict__ P, int nsteps)
{
  __shared__ __align__(16) char smem[34816];
  char* const A0 = smem;              // 128 rows * 72B (64B data + 8B pad)
  char* const A1 = smem + 9216;
  char* const B0 = smem + 18432;      // 128 rows * 64B, chunk c at pos c^((row>>1)&3)
  char* const B1 = smem + 26624;

  const int t = threadIdx.x;
  const int i0 = blockIdx.x * 128;
  const int j0 = blockIdx.y * 128;
  const int z  = blockIdx.z;
  const int lane = t & 63;
  const int q = lane >> 4, l15 = lane & 15;
  const int w = t >> 6;
  const int wm = w >> 1, wn = w & 1;        // 2x2 waves; wave tile 64(m) x 64(n)

  // staging roles
  const int arow = t >> 1, ahalf = t & 1;   // A: 128 rows x 2 halves of 16 floats
  const int brow = t >> 2;                  // B: rows (t>>2) + r*64
  const int bchunk = (t & 3) ^ ((t >> 3) & 3);  // global-side swizzled 16B chunk

  f32x4 acc[4][4] = {};
  const int kbase0 = z * (nsteps << 5);

  // two rotating A-prefetch register sets (2 steps ahead)
  float4 aX0, aX1, aX2, aX3, aY0, aY1, aY2, aY3;

#define A_SRC(gk) ((gk) < 8192 \
    ? a_ud + (size_t)(i0 + arow) * 8192 + (gk) + ahalf * 16 \
    : ((gk) < 16384 \
      ? a_lr + (size_t)(i0 + arow) * 8192 + ((gk) - 8192) + ahalf * 16 \
      : x + (size_t)(i0 + arow) * 512 + ((gk) - 16384) + ahalf * 16))

#define LOAD_A(R0, R1, R2, R3, gk) { \
    const float* as_ = A_SRC(gk); \
    R0 = ((const float4*)as_)[0]; R1 = ((const float4*)as_)[1]; \
    R2 = ((const float4*)as_)[2]; R3 = ((const float4*)as_)[3]; }

#define LOAD_B(dstB, gk) { \
    gload16(Yt + (size_t)(j0 + brow) * 16896 + (gk) + bchunk * 8, (dstB) + t * 16); \
    gload16(Yt + (size_t)(j0 + brow + 64) * 16896 + (gk) + bchunk * 8, (dstB) + 4096 + t * 16); }

#define PACK_A(dstA, R0, R1, R2, R3) { \
    uint4 p0_, p1_; \
    p0_.x = pack2t(R0.x, R0.y); p0_.y = pack2t(R0.z, R0.w); \
    p0_.z = pack2t(R1.x, R1.y); p0_.w = pack2t(R1.z, R1.w); \
    p1_.x = pack2t(R2.x, R2.y); p1_.y = pack2t(R2.z, R2.w); \
    p1_.z = pack2t(R3.x, R3.y); p1_.w = pack2t(R3.z, R3.w); \
    *(uint4*)((dstA) + arow * 72 + ahalf * 32) = p0_; \
    *(uint4*)((dstA) + arow * 72 + ahalf * 32 + 16) = p1_; }

  // prologue: A(0)->X, B(0)->B0, A(1)->Y; pack X into A0; retire B(0), keep A(1).
  // vm queue after: [A(1) x4]
  LOAD_A(aX0, aX1, aX2, aX3, kbase0);
  __builtin_amdgcn_sched_barrier(0);
  LOAD_B(B0, kbase0);
  __builtin_amdgcn_sched_barrier(0);
  LOAD_A(aY0, aY1, aY2, aY3, kbase0 + 32);
  __builtin_amdgcn_sched_barrier(0);
  PACK_A(A0, aX0, aX1, aX2, aX3);          // compiler-inserted wait covers X regs
  asm volatile("s_waitcnt vmcnt(4) lgkmcnt(0)" ::: "memory");
  __builtin_amdgcn_sched_barrier(0);
  __builtin_amdgcn_s_barrier();
  __builtin_amdgcn_sched_barrier(0);

  // body s: compute C(s) from buf[s&1]; issue B(s+1) then A(s+2); pack A(s+1);
  // end wait retires B(s+1) (vmcnt(4) leaves A(s+2) in flight; tail: vmcnt(0)).
#define K5_BODY(s_, LX0, LX1, LX2, LX3, PX0, PX1, PX2, PX3) { \
    const int s__ = (s_); \
    char* const cA_ = (s__ & 1) ? A1 : A0; \
    char* const cB_ = (s__ & 1) ? B1 : B0; \
    char* const nA_ = (s__ & 1) ? A0 : A1; \
    char* const nB_ = (s__ & 1) ? B0 : B1; \
    const bool h1_ = (s__ + 1 < nsteps); \
    const bool h2_ = (s__ + 2 < nsteps); \
    if (h1_) { LOAD_B(nB_, kbase0 + ((s__ + 1) << 5)); } \
    __builtin_amdgcn_sched_barrier(0); \
    if (h2_) { LOAD_A(LX0, LX1, LX2, LX3, kbase0 + ((s__ + 2) << 5)); } \
    __builtin_amdgcn_sched_barrier(0); \
    short8 af_[4], bf_[4]; \
    _Pragma("unroll") \
    for (int mi_ = 0; mi_ < 4; ++mi_) \
      af_[mi_] = *(const short8*)(cA_ + (wm * 64 + mi_ * 16 + l15) * 72 + q * 16); \
    _Pragma("unroll") \
    for (int ni_ = 0; ni_ < 4; ++ni_) { \
      const int j_ = wn * 64 + ni_ * 16 + l15; \
      bf_[ni_] = *(const short8*)(cB_ + j_ * 64 + ((q ^ ((j_ >> 1) & 3)) * 16)); \
    } \
    _Pragma("unroll") \
    for (int mi_ = 0; mi_ < 4; ++mi_) \
      _Pragma("unroll") \
      for (int ni_ = 0; ni_ < 4; ++ni_) \
        acc[mi_][ni_] = __builtin_amdgcn_mfma_f32_16x16x32_bf16(af_[mi_], bf_[ni_], acc[mi_][ni_], 0, 0, 0); \
    if (h1_) { PACK_A(nA_, PX0, PX1, PX2, PX3); } \
    if (h2_) { asm volatile("s_waitcnt vmcnt(4) lgkmcnt(0)" ::: "memory"); } \
    else     { asm volatile("s_waitcnt vmcnt(0) lgkmcnt(0)" ::: "memory"); } \
    __builtin_amdgcn_sched_barrier(0); \
    __builtin_amdgcn_s_barrier(); \
    __builtin_amdgcn_sched_barrier(0); \
  }

  for (int s = 0; s < nsteps; s += 2) {
    K5_BODY(s,     aX0, aX1, aX2, aX3, aY0, aY1, aY2, aY3);  // load A(s+2)->X, pack Y=A(s+1)
    K5_BODY(s + 1, aY0, aY1, aY2, aY3, aX0, aX1, aX2, aX3);  // load A(s+3)->Y, pack X=A(s+2)
  }
#undef K5_BODY
#undef PACK_A
#undef LOAD_B
#undef LOAD_A
#undef A_SRC

  float* dst = z ? P + (size_t)(z - 1) * 4194304 : out;
#pragma unroll
  for (int ni = 0; ni < 4; ++ni) {
    const int jl = j0 + wn * 64 + ni * 16 + l15;
#pragma unroll
    for (int mi = 0; mi < 4; ++mi)
#pragma unroll
      for (int r = 0; r < 4; ++r) {
        const int il = i0 + wm * 64 + mi * 16 + q * 4 + r;
        dst[(size_t)il * 512 + jl] = acc[mi][ni][r];
      }
  }
}

// ---------------- K6: combine split-K partials + row_add + relu ----------------
__global__ __launch_bounds__(256) void k6_combine(
    const float* __restrict__ P, const float* __restrict__ row_add,
    float* __restrict__ out, int npart)
{
  const int idx = blockIdx.x * 256 + threadIdx.x;     // float4 index, 1048576 total
  float4 a = ((const float4*)out)[idx];
  for (int p = 0; p < npart; ++p) {
    const float4 v = ((const float4*)P)[(size_t)p * 1048576 + idx];
    a.x += v.x; a.y += v.y; a.z += v.z; a.w += v.w;
  }
  const float4 r = ((const float4*)row_add)[idx & 127];
  float4 o;
  o.x = fmaxf(a.x + r.x, 0.f);
  o.y = fmaxf(a.y + r.y, 0.f);
  o.z = fmaxf(a.z + r.z, 0.f);
  o.w = fmaxf(a.w + r.w, 0.f);
  ((float4*)out)[idx] = o;
}

extern "C" void kernel_launch(void* const* d_in, const int* in_sizes, int n_in,
                              void* d_out, int out_size, void* d_ws, size_t ws_size,
                              hipStream_t stream) {
  (void)in_sizes; (void)n_in; (void)out_size;
  const float* x    = (const float*)d_in[0];
  const float* mask = (const float*)d_in[1];
  const float* a_ud = (const float*)d_in[2];
  const float* a_lr = (const float*)d_in[3];
  const float* W    = (const float*)d_in[4];
  const float* b    = (const float*)d_in[5];
  const float* W_ud = (const float*)d_in[6];
  const float* b_ud = (const float*)d_in[7];
  const float* W_lr = (const float*)d_in[8];
  const float* b_lr = (const float*)d_in[9];
  const float* W_g  = (const float*)d_in[10];
  const float* b_g  = (const float*)d_in[11];
  const float* W_go = (const float*)d_in[12];
  const float* b_go = (const float*)d_in[13];
  float* out = (float*)d_out;

  char* ws = (char*)d_ws;
  uint16_t* xb     = (uint16_t*)(ws);
  uint16_t* Yt     = (uint16_t*)(ws + 8388608);
  uint16_t* Wb1    = (uint16_t*)(ws + 25690112);
  float*    colsum = (float*)(ws + 27262976);
  float*    rowadd = (float*)(ws + 27265024);
  float*    P      = (float*)(ws + 27267072);

  // ws gate: z=4 needs 3 partials (77.6 MB); fall back to z=2 (1 partial, 44 MB proven).
  const int Z = (ws_size >= 77598720u) ? 4 : 2;
  const int nsteps = (16896 / Z) / 32;

  hipMemsetAsync(colsum, 0, 512 * sizeof(float), stream);
  k1_convert<<<2560, 256, 0, stream>>>(x, W, W_ud, W_lr, W_g, xb, Yt, Wb1);
  k2_gemm1<<<dim3(64, 12), 256, 0, stream>>>(xb, Wb1, mask, b_g, Yt, colsum);
  k4_finalize<<<8, 256, 0, stream>>>(colsum, mask, b, b_ud, b_lr, W_go, b_go,
                                     rowadd, out + 4194304);
  k5_gemm_big<<<dim3(64, 4, Z), 256, 0, stream>>>(a_ud, a_lr, x, Yt, out, P, nsteps);
  k6_combine<<<4096, 256, 0, stream>>>(P, rowadd, out, Z - 1);
}